// Round 3
// baseline (1063.804 us; speedup 1.0000x reference)
//
#include <hip/hip_runtime.h>
#include <math.h>

// TopExpertsRouter on MI355X (gfx950) — two-phase, bit-identical numerics to
// the passing kernels: per-(token,expert) logit = 8 chunks of ascending-512
// fmaf chains (xyzw within float4), chunks summed ascending in finish.
//
// Round-2 post-mortem: 8x8 LDS-tiled gemm hit ~158us (from 275), but the
// structure is LDS-pipe-bound: 16 ds_read_b128/d4-step (~1KB return path
// each) ~= the fmac cycles -> ~2x the 55us VALU floor, + 16 vmcnt(0) barrier
// drains. This round removes LDS from the dataflow entirely:
//
//   * lane = token. Each thread owns ONE token and acc[64] (one per expert).
//   * x: lane-private global loads (4x b128 per 16-dim piece, 64B-aligned
//     per lane; L2 absorbs the 128B-line split across adjacent pieces).
//   * W: addresses are wave-uniform (uniform e/p loops, uniform chunk) ->
//     compiler emits scalar s_load (scalar pipe; costs no VALU, no LDS) and
//     v_fmac_f32 acc, s_w, v_x (one SGPR operand is legal).
//   * zero LDS, zero __syncthreads, zero vmcnt(0) drains; 64 independent
//     fmaf chains per lane = perfect ILP for the scheduler.
//   * parallelism: 16384 tokens x 8 chunks / 256 thr = 512 blocks
//     (2048 waves, ~8 waves/CU); no LDS -> occupancy VGPR-limited only.
//   * partial store [chunk][e][token]: lane-consecutive tokens -> 256B
//     coalesced stores, same layout as all passing rounds.
//
// Accumulation order per acc: single ascending fmaf chain over d=0..511 of
// its chunk (32 pieces x 16 dims, xyzw within float4) — identical to the
// passing kernels. Phase 2 (router_finish) byte-identical.

constexpr int D  = 4096;
constexpr int E  = 64;
constexpr int K  = 8;

__global__ __launch_bounds__(256, 2) void router_gemm(
    const float* __restrict__ x, const float* __restrict__ W,
    float* __restrict__ partial, int ntok, int dlen, int ntiles)
{
    // ntiles = ntok/256 token-blocks; grid = ntiles * nchunks
    const int tid   = threadIdx.x;
    const int tile  = blockIdx.x % ntiles;
    const int chunk = blockIdx.x / ntiles;
    const int t  = tile * 256 + tid;     // this thread's token
    const int d0 = chunk * dlen;

    const float* xp = x + (size_t)t * D + d0;
    const float* Wc = W + d0;

    float acc[E];
#pragma unroll
    for (int e = 0; e < E; ++e) acc[e] = 0.f;

    const int np = dlen / 16;            // 16-dim pieces
    for (int p = 0; p < np; ++p) {
        float4 xv[4];
#pragma unroll
        for (int q = 0; q < 4; ++q)
            xv[q] = *(const float4*)(xp + p * 16 + q * 4);

        const float* wp = Wc + p * 16;   // uniform across the wave
#pragma unroll
        for (int e = 0; e < E; ++e) {
            const float* w = wp + (size_t)e * D;   // uniform -> s_load
            float a = acc[e];
            a = fmaf(xv[0].x, w[0],  a);
            a = fmaf(xv[0].y, w[1],  a);
            a = fmaf(xv[0].z, w[2],  a);
            a = fmaf(xv[0].w, w[3],  a);
            a = fmaf(xv[1].x, w[4],  a);
            a = fmaf(xv[1].y, w[5],  a);
            a = fmaf(xv[1].z, w[6],  a);
            a = fmaf(xv[1].w, w[7],  a);
            a = fmaf(xv[2].x, w[8],  a);
            a = fmaf(xv[2].y, w[9],  a);
            a = fmaf(xv[2].z, w[10], a);
            a = fmaf(xv[2].w, w[11], a);
            a = fmaf(xv[3].x, w[12], a);
            a = fmaf(xv[3].y, w[13], a);
            a = fmaf(xv[3].z, w[14], a);
            a = fmaf(xv[3].w, w[15], a);
            acc[e] = a;
        }
    }

    // partial[chunk][e][token]: lanes hold consecutive tokens -> coalesced
    float* dst = partial + (size_t)chunk * E * ntok + t;
#pragma unroll
    for (int e = 0; e < E; ++e)
        dst[(size_t)e * ntok] = acc[e];
}

template <int NC>
__global__ __launch_bounds__(256) void router_finish(
    const float* __restrict__ partial, float* __restrict__ out, int ntok)
{
    __shared__ float ls[64][E + 4];

    const int tid = threadIdx.x;
    const int t0  = blockIdx.x * 64;
    const int t   = tid & 63;
    const int eg  = tid >> 6;

#pragma unroll
    for (int j = 0; j < 16; ++j) {
        const int e = eg * 16 + j;
        const float* p = partial + (size_t)e * ntok + t0 + t;
        float v = p[0];
#pragma unroll
        for (int c = 1; c < NC; ++c)            // ascending: bit-equal
            v += p[(size_t)c * E * ntok];
        ls[t][e] = v;
    }
    __syncthreads();

    if (tid < 64) {
        const int n = t0 + tid;
        float l[E];
#pragma unroll
        for (int g = 0; g < 16; ++g) {
            const float4 v = *(const float4*)&ls[tid][g * 4];
            l[g * 4 + 0] = v.x; l[g * 4 + 1] = v.y;
            l[g * 4 + 2] = v.z; l[g * 4 + 3] = v.w;
        }

        // ---- identical epilogue to passing rounds ----
        float m = l[0];
#pragma unroll
        for (int e = 1; e < E; ++e) m = fmaxf(m, l[e]);
        float sum = 0.f;
#pragma unroll
        for (int e = 0; e < E; ++e) { l[e] = expf(l[e] - m); sum += l[e]; }
        const float inv = 1.f / sum;
#pragma unroll
        for (int e = 0; e < E; ++e) l[e] *= inv;

        float* probs = out + (size_t)ntok * 2 * K + (size_t)n * E;
#pragma unroll
        for (int g = 0; g < 16; ++g)
            *(float4*)&probs[g * 4] =
                make_float4(l[g * 4], l[g * 4 + 1], l[g * 4 + 2], l[g * 4 + 3]);

        float vals[K];
        int   idxs[K];
        float ts = 0.f;
        for (int k = 0; k < K; ++k) {
            float best = -1.f;
            int   bi   = 0;
#pragma unroll
            for (int e = 0; e < E; ++e)
                if (l[e] > best) { best = l[e]; bi = e; }
            vals[k] = best;
            idxs[k] = bi;
            ts += best;
#pragma unroll
            for (int e = 0; e < E; ++e)
                if (e == bi) l[e] = -1.f;
        }
        const float winv = 1.f / (ts + 1e-9f);

        float* oi = out + (size_t)n * K;
        float* ow = out + (size_t)ntok * K + (size_t)n * K;
#pragma unroll
        for (int k = 0; k < K; ++k) {
            oi[k] = (float)idxs[k];
            ow[k] = vals[k] * winv;
        }
    }
}

extern "C" void kernel_launch(void* const* d_in, const int* in_sizes, int n_in,
                              void* d_out, int out_size, void* d_ws, size_t ws_size,
                              hipStream_t stream)
{
    const float* x = (const float*)d_in[0];
    const float* W = (const float*)d_in[1];
    float* out = (float*)d_out;

    const int ntok = in_sizes[0] / D;  // 16384

    // identical nchunks policy to passing rounds (bit-exactness anchor)
    int nchunks = 8;
    while (nchunks > 1 &&
           (size_t)nchunks * E * (size_t)ntok * sizeof(float) > ws_size)
        nchunks >>= 1;
    const int dlen   = D / nchunks;
    const int ntiles = ntok / 256;     // 256 tokens (threads) per block

    float* partial = (float*)d_ws;

    hipLaunchKernelGGL(router_gemm, dim3(ntiles * nchunks), dim3(256), 0, stream,
                       x, W, partial, ntok, dlen, ntiles);
    switch (nchunks) {
        case 8:
            hipLaunchKernelGGL(router_finish<8>, dim3(ntok / 64), dim3(256), 0,
                               stream, partial, out, ntok);
            break;
        case 4:
            hipLaunchKernelGGL(router_finish<4>, dim3(ntok / 64), dim3(256), 0,
                               stream, partial, out, ntok);
            break;
        case 2:
            hipLaunchKernelGGL(router_finish<2>, dim3(ntok / 64), dim3(256), 0,
                               stream, partial, out, ntok);
            break;
        default:
            hipLaunchKernelGGL(router_finish<1>, dim3(ntok / 64), dim3(256), 0,
                               stream, partial, out, ntok);
            break;
    }
}

// Round 4
// 748.196 us; speedup vs baseline: 1.4218x; 1.4218x over previous
//
#include <hip/hip_runtime.h>
#include <math.h>

// TopExpertsRouter on MI355X (gfx950) — two-phase.
// GEMM: bit-identical numerics to the passing rounds (per-(token,expert)
// logit = 8 chunks of ascending-512 fmaf chains, xyzw within float4; chunks
// summed ascending in finish).
//
// Round-3 post-mortem: no-LDS acc[64] spilled (VGPR=52 < 64 needed; WRITE_SIZE
// 108MB vs 32MB real -> scratch traffic; 800us). Reverted to the round-2
// LDS-tiled 8x8 structure (158us) and removed its remaining stall:
//   * round-2 paid 2 barriers per k-subtile with vmcnt(0) drained BETWEEN
//     stage and compute -> HBM latency fully exposed each subtile.
//   * now: double-buffered BK=16 subtiles; per subtile ONE __syncthreads();
//     next subtile's global_load_lds issued right after the barrier and
//     BEFORE computing the current buffer (guide T3 minimum-2-phase) -> load
//     latency hides under ~2k cyc of fmac; barrier count halves.
//   * XOR swizzle for BK=16: col4' = d4 ^ (row&3); broadcast reads land
//     2-way bank-aliased (free, m136). global_load_lds: linear LDS dest
//     (uniform base + lane*16B), pre-swizzled global source col.
//   * LDS = 2x(8KB x + 4KB w) = 24KB, aliased by cs[64][132]=33.8KB -> block
//     LDS 33.8KB -> 4 blocks/CU (8 waves), as in round 2.
// FINISH: phase-1 float4 loads (ascending chunk adds per element, bit-equal);
// epilogue parallelized 4 lanes/token: lane-local top over 16 experts +
// 2x shfl_xor merge with exact (greater | equal&lower-index) tie-break ->
// identical idx/vals to the serial scan. Softmax denom is a lane-partial +
// butterfly sum: a common positive scale per token -> top-k order provably
// unchanged; probs/weights drift ~1ulp.

constexpr int D  = 4096;
constexpr int E  = 64;
constexpr int K  = 8;
constexpr int BT = 128;  // tokens per gemm block
constexpr int BK = 16;   // d sub-tile (floats)
constexpr int CS = 132;  // cs[e][token] stride (2-way alias, free)

typedef const unsigned int __attribute__((address_space(1))) gu32;
typedef unsigned int       __attribute__((address_space(3))) lu32;

__device__ __forceinline__ void gload16(const float* src, float* lds_dst)
{
    __builtin_amdgcn_global_load_lds((gu32*)src, (lu32*)lds_dst, 16, 0, 0);
}

__global__ __launch_bounds__(128, 2) void router_gemm(
    const float* __restrict__ x, const float* __restrict__ W,
    float* __restrict__ partial, int ntok, int dlen, int ntiles)
{
    // floats: xs0 [0,2048) xs1 [2048,4096) ws0 [4096,5120) ws1 [5120,6144)
    // whole buffer reused afterwards as cs[64][132] = 8448 floats
    __shared__ float smem[8448];

    const int tid   = threadIdx.x;
    const int tile  = blockIdx.x % ntiles;
    const int chunk = blockIdx.x / ntiles;
    const int t0 = tile * BT;
    const int d0 = chunk * dlen;

    // ---- staging map: lane l -> row lr=l>>2 (of 16-row group), col4 l&3 ----
    const int l   = tid & 63;
    const int wv  = tid >> 6;        // wave 0..1
    const int lr  = l >> 2;          // 0..15
    const int lc  = l & 3;           // col4 written (linear)
    const int swc = lc ^ (lr & 3);   // col4 read from global (pre-swizzle)

    const float* xg = x + (size_t)(t0 + wv * 64 + lr) * D + d0 + swc * 4;
    const float* wg = W + (size_t)(wv * 32 + lr) * D + d0 + swc * 4;

    // ---- compute map: experts e = tx + 8j, tokens t = ty + 16i ----
    const int tx  = tid & 7;
    const int ty  = tid >> 3;        // 0..15
    const int tym = (ty & 3);
    const int txm = (tx & 3);

    float acc[8][8];
#pragma unroll
    for (int i = 0; i < 8; ++i)
#pragma unroll
        for (int j = 0; j < 8; ++j) acc[i][j] = 0.f;

    const int nk = dlen / BK;        // 32 (nchunks=8) — always even

    // STAGE subtile kk into buffer b: 4 x-gloads + 2 w-gloads per thread.
    // LDS dest is wave-uniform (HW adds lane*16B): row wv*64+i*16+lr, col4 lc.
#define STAGE(kk, b)                                                         \
    {                                                                        \
        const float* px = xg + (size_t)(kk) * BK;                            \
        float* bx = smem + (b) * 2048 + wv * 1024;                           \
        gload16(px,                     bx);                                 \
        gload16(px + (size_t)16 * D,    bx + 256);                           \
        gload16(px + (size_t)32 * D,    bx + 512);                           \
        gload16(px + (size_t)48 * D,    bx + 768);                           \
        const float* pw = wg + (size_t)(kk) * BK;                            \
        float* bw = smem + 4096 + (b) * 1024 + wv * 512;                     \
        gload16(pw,                     bw);                                 \
        gload16(pw + (size_t)16 * D,    bw + 256);                           \
    }

#define COMPUTE(b)                                                           \
    {                                                                        \
        const float* xb = smem + (b) * 2048 + ty * 16;                       \
        const float* wb = smem + 4096 + (b) * 1024 + tx * 16;                \
        _Pragma("unroll")                                                    \
        for (int d4 = 0; d4 < 4; ++d4) {                                     \
            const int cxo = (d4 ^ tym) * 4;                                  \
            float4 xf[8];                                                    \
            _Pragma("unroll")                                                \
            for (int i = 0; i < 8; ++i)                                      \
                xf[i] = *(const float4*)(xb + i * 256 + cxo);                \
            const int cwo = (d4 ^ txm) * 4;                                  \
            _Pragma("unroll")                                                \
            for (int j = 0; j < 8; ++j) {                                    \
                const float4 wf = *(const float4*)(wb + j * 128 + cwo);      \
                _Pragma("unroll")                                            \
                for (int i = 0; i < 8; ++i) {                                \
                    float a = acc[i][j];                                     \
                    a = fmaf(xf[i].x, wf.x, a);                              \
                    a = fmaf(xf[i].y, wf.y, a);                              \
                    a = fmaf(xf[i].z, wf.z, a);                              \
                    a = fmaf(xf[i].w, wf.w, a);                              \
                    acc[i][j] = a;                                           \
                }                                                            \
            }                                                                \
        }                                                                    \
    }

    STAGE(0, 0);
    for (int k = 0; k + 2 <= nk; k += 2) {
        __syncthreads();                 // stage(k) arrived; compute(k-1) done
        STAGE(k + 1, 1);                 // prefetch during compute(k)
        COMPUTE(0);
        __syncthreads();                 // stage(k+1) arrived; compute(k) done
        if (k + 2 < nk) STAGE(k + 2, 0); // prefetch during compute(k+1)
        COMPUTE(1);
    }
#undef STAGE
#undef COMPUTE

    // acc -> LDS transpose -> coalesced 256B partial stores [chunk][e][token]
    __syncthreads();
    float* cs = smem;
#pragma unroll
    for (int j = 0; j < 8; ++j)
#pragma unroll
        for (int i = 0; i < 8; ++i)
            cs[(tx + 8 * j) * CS + (ty + 16 * i)] = acc[i][j];
    __syncthreads();

#pragma unroll
    for (int jj = 0; jj < 32; ++jj) {
        const int e = wv * 32 + jj;
        float* dst = partial + ((size_t)chunk * E + e) * ntok + t0;
        dst[l]      = cs[e * CS + l];
        dst[l + 64] = cs[e * CS + l + 64];
    }
}

template <int NC>
__global__ __launch_bounds__(256) void router_finish(
    const float* __restrict__ partial, float* __restrict__ out, int ntok)
{
    __shared__ float ls[64][E + 4];

    const int tid = threadIdx.x;
    const int t0  = blockIdx.x * 64;

    // ---- phase 1: float4 over tokens; chunks summed ascending (bit-equal) --
    const int t4 = tid & 15;         // token quad: tokens t4*4 .. t4*4+3
    const int eb = tid >> 4;         // 0..15
#pragma unroll
    for (int g = 0; g < 4; ++g) {
        const int e = eb + 16 * g;
        const float* p = partial + (size_t)e * ntok + t0 + t4 * 4;
        float4 a = *(const float4*)p;
#pragma unroll
        for (int c = 1; c < NC; ++c) {
            const float4 b = *(const float4*)(p + (size_t)c * E * ntok);
            a.x += b.x; a.y += b.y; a.z += b.z; a.w += b.w;
        }
        ls[t4 * 4 + 0][e] = a.x;
        ls[t4 * 4 + 1][e] = a.y;
        ls[t4 * 4 + 2][e] = a.z;
        ls[t4 * 4 + 3][e] = a.w;
    }
    __syncthreads();

    // ---- phase 2: 4 lanes per token ----
    const int tt = tid >> 2;         // token 0..63
    const int q  = tid & 3;          // expert quarter: e = q*16 + eo
    const int n  = t0 + tt;

    float v[16];
#pragma unroll
    for (int g = 0; g < 4; ++g) {
        const float4 r = *(const float4*)&ls[tt][q * 16 + g * 4];
        v[g * 4 + 0] = r.x; v[g * 4 + 1] = r.y;
        v[g * 4 + 2] = r.z; v[g * 4 + 3] = r.w;
    }

    // max: bit-exact (fmax is order-independent)
    float m = v[0];
#pragma unroll
    for (int e = 1; e < 16; ++e) m = fmaxf(m, v[e]);
    m = fmaxf(m, __shfl_xor(m, 1));
    m = fmaxf(m, __shfl_xor(m, 2));

    // exp + sum (lane-partial ascending, then butterfly — common scale/token)
    float s = 0.f;
#pragma unroll
    for (int e = 0; e < 16; ++e) { v[e] = expf(v[e] - m); s += v[e]; }
    s += __shfl_xor(s, 1);
    s += __shfl_xor(s, 2);
    const float inv = 1.f / s;
#pragma unroll
    for (int e = 0; e < 16; ++e) v[e] *= inv;

    float* probs = out + (size_t)ntok * 2 * K + (size_t)n * E;
#pragma unroll
    for (int g = 0; g < 4; ++g)
        *(float4*)&probs[q * 16 + g * 4] =
            make_float4(v[g * 4], v[g * 4 + 1], v[g * 4 + 2], v[g * 4 + 3]);

    // top-8: lane-local first-max over 16, then 2-step merge preferring
    // (greater) | (equal & lower index) — identical to serial ascending scan.
    float vals[K];
    int   idxs[K];
    float ts = 0.f;
    for (int k = 0; k < K; ++k) {
        float b  = v[0];
        int   bi = q * 16;
#pragma unroll
        for (int e = 1; e < 16; ++e)
            if (v[e] > b) { b = v[e]; bi = q * 16 + e; }
        float ob;
        int   obi;
        ob  = __shfl_xor(b, 1);
        obi = __shfl_xor(bi, 1);
        if (ob > b || (ob == b && obi < bi)) { b = ob; bi = obi; }
        ob  = __shfl_xor(b, 2);
        obi = __shfl_xor(bi, 2);
        if (ob > b || (ob == b && obi < bi)) { b = ob; bi = obi; }
        vals[k] = b;
        idxs[k] = bi;
        ts += b;
        const int lo = bi - q * 16;      // mask owner's copy (unrolled cmp)
#pragma unroll
        for (int e = 0; e < 16; ++e)
            if (e == lo) v[e] = -1.f;    // lo in [0,16) only for owning lane
    }
    const float winv = 1.f / (ts + 1e-9f);

    if (q == 0) {
        float* oi = out + (size_t)n * K;
        float* ow = out + (size_t)ntok * K + (size_t)n * K;
#pragma unroll
        for (int k = 0; k < K; ++k) {
            oi[k] = (float)idxs[k];
            ow[k] = vals[k] * winv;
        }
    }
}

extern "C" void kernel_launch(void* const* d_in, const int* in_sizes, int n_in,
                              void* d_out, int out_size, void* d_ws, size_t ws_size,
                              hipStream_t stream)
{
    const float* x = (const float*)d_in[0];
    const float* W = (const float*)d_in[1];
    float* out = (float*)d_out;

    const int ntok = in_sizes[0] / D;  // 16384

    // identical nchunks policy to passing rounds (bit-exactness anchor)
    int nchunks = 8;
    while (nchunks > 1 &&
           (size_t)nchunks * E * (size_t)ntok * sizeof(float) > ws_size)
        nchunks >>= 1;
    const int dlen   = D / nchunks;
    const int ntiles = ntok / BT;

    float* partial = (float*)d_ws;

    hipLaunchKernelGGL(router_gemm, dim3(ntiles * nchunks), dim3(128), 0, stream,
                       x, W, partial, ntok, dlen, ntiles);
    switch (nchunks) {
        case 8:
            hipLaunchKernelGGL(router_finish<8>, dim3(ntok / 64), dim3(256), 0,
                               stream, partial, out, ntok);
            break;
        case 4:
            hipLaunchKernelGGL(router_finish<4>, dim3(ntok / 64), dim3(256), 0,
                               stream, partial, out, ntok);
            break;
        case 2:
            hipLaunchKernelGGL(router_finish<2>, dim3(ntok / 64), dim3(256), 0,
                               stream, partial, out, ntok);
            break;
        default:
            hipLaunchKernelGGL(router_finish<1>, dim3(ntok / 64), dim3(256), 0,
                               stream, partial, out, ntok);
            break;
    }
}